// Round 4
// baseline (4122.537 us; speedup 1.0000x reference)
//
#include <hip/hip_runtime.h>
#include <hip/hip_bf16.h>

#define DIN 49
#define HIN 32
#define WIN 64
#define CIN 32
#define DOUT 193
#define HOUT 256
#define WOUT 512
#define NPIX (HOUT * WOUT)      // 131072
#define NUPS (DOUT * NPIX)      // 25296896
#define NCONV (DIN * HIN * WIN) // 100352
#define DSPLIT 48
#define NZ 5 // 4 full z-slices of 48 + one 1-plane slice (d=192)

// LGA LDS geometry: d-contiguous per pixel.
#define ROWS 20      // h halo rows
#define COLS 32      // staged w halo (16B-aligned segments)
#define ROWSTRIDE 33 // pixel-row stride in pixels (padded: 33*12 % 32 == 12)
#define PIXSTRIDE 12 // words per pixel (10 planes + 2 pad; 48 B, 16B-aligned)
#define NJOBS 800    // 10 planes * 20 rows * 4 segs
#define SUWORDS 7920

// ---------------------------------------------------------------------------
// Kernel 1: 3x3x3 conv, 32 -> 1 channels, zero pad 1, fp32 accumulate.
// ---------------------------------------------------------------------------
__global__ void conv3d_kernel(const float* __restrict__ x,
                              const float* __restrict__ w,
                              float* __restrict__ c) {
    __shared__ float ws[CIN * 27];
    for (int t = threadIdx.x; t < CIN * 27; t += blockDim.x)
        ws[t] = w[t];
    __syncthreads();

    int idx = blockIdx.x * blockDim.x + threadIdx.x;
    if (idx >= NCONV) return;
    int wq = idx % WIN;
    int t2 = idx / WIN;
    int hq = t2 % HIN;
    int dq = t2 / HIN;

    float acc = 0.f;
    for (int ci = 0; ci < CIN; ++ci) {
        const float* xb = x + ci * NCONV;
        const float* wb = ws + ci * 27;
#pragma unroll
        for (int kd = 0; kd < 3; ++kd) {
            int zd = dq + kd - 1;
            if (zd < 0 || zd >= DIN) continue;
#pragma unroll
            for (int kh = 0; kh < 3; ++kh) {
                int zh = hq + kh - 1;
                if (zh < 0 || zh >= HIN) continue;
#pragma unroll
                for (int kw = 0; kw < 3; ++kw) {
                    int zw = wq + kw - 1;
                    if (zw < 0 || zw >= WIN) continue;
                    acc += xb[(zd * HIN + zh) * WIN + zw] *
                           wb[(kd * 3 + kh) * 3 + kw];
                }
            }
        }
    }
    c[idx] = acc;
}

// ---------------------------------------------------------------------------
// Kernel 2: trilinear upsample, 8 outputs/thread along w, uint4 stores.
// ---------------------------------------------------------------------------
__global__ void upsample_kernel(const float* __restrict__ c,
                                __hip_bfloat16* __restrict__ u) {
    int t = blockIdx.x * blockDim.x + threadIdx.x;
    int wc = t & 63;
    int rest = t >> 6;
    int hh = rest & 255;
    int dd = rest >> 8;
    if (dd >= DOUT) return;

    float fd = (dd + 0.5f) * (49.0f / 193.0f) - 0.5f;
    fd = fminf(fmaxf(fd, 0.f), (float)(DIN - 1));
    int d0 = min((int)fd, DIN - 2);
    float ad = fd - (float)d0;

    float fh = (hh + 0.5f) * 0.125f - 0.5f;
    fh = fminf(fmaxf(fh, 0.f), (float)(HIN - 1));
    int h0 = min((int)fh, HIN - 2);
    float ah = fh - (float)h0;

    int cm1 = max(wc - 1, 0);
    int cp1 = min(wc + 1, WIN - 1);
    const float* p00 = c + (d0 * HIN + h0) * WIN;
    const float* p01 = p00 + WIN;
    const float* p10 = p00 + HIN * WIN;
    const float* p11 = p10 + WIN;

    float a[3];
    {
        float q00, q01, q10, q11;
        q00 = p00[cm1]; q01 = p01[cm1]; q10 = p10[cm1]; q11 = p11[cm1];
        a[0] = (q00 + ah * (q01 - q00)) * (1.f - ad) +
               (q10 + ah * (q11 - q10)) * ad;
        q00 = p00[wc]; q01 = p01[wc]; q10 = p10[wc]; q11 = p11[wc];
        a[1] = (q00 + ah * (q01 - q00)) * (1.f - ad) +
               (q10 + ah * (q11 - q10)) * ad;
        q00 = p00[cp1]; q01 = p01[cp1]; q10 = p10[cp1]; q11 = p11[cp1];
        a[2] = (q00 + ah * (q01 - q00)) * (1.f - ad) +
               (q10 + ah * (q11 - q10)) * ad;
    }

    union {
        unsigned short us[8];
        uint4 v4;
    } pk;
#pragma unroll
    for (int i = 0; i < 8; ++i) {
        float fw = (float)(wc * 8 + i) * 0.125f + (0.0625f - 0.5f);
        fw = fminf(fmaxf(fw, 0.f), (float)(WIN - 1));
        int w0 = min((int)fw, WIN - 2);
        float aw = fw - (float)w0;
        int idx = w0 - (wc - 1);
        float lo = (idx == 0) ? a[0] : a[1];
        float hi = (idx == 0) ? a[1] : a[2];
        float v = lo + aw * (hi - lo);
        __hip_bfloat16 b = __float2bfloat16(v);
        unsigned short usv;
        __builtin_memcpy(&usv, &b, 2);
        pk.us[i] = usv;
    }
    *((uint4*)(u + (size_t)dd * NPIX + hh * WOUT + wc * 8)) = pk.v4;
}

// ---------------------------------------------------------------------------
// LGA: 16x16 pixel tile x 48 d-planes per block. d-contiguous LDS, wide
// ds_reads, coalesced 16B double-buffered staging, bf16-packed guidance.
// ---------------------------------------------------------------------------
__device__ __forceinline__ unsigned short bf16bits(float f) {
    __hip_bfloat16 h = __float2bfloat16(f);
    unsigned short b;
    __builtin_memcpy(&b, &h, 2);
    return b;
}

__global__ __launch_bounds__(256, 3) void lga_kernel(
    const __hip_bfloat16* __restrict__ xin,
    const float* __restrict__ lg1,
    __hip_bfloat16* __restrict__ yout) {
    const int tid = threadIdx.x;
    const int tx = tid & 15;
    const int ty = tid >> 4;
    const int w0p = blockIdx.x * 16;
    const int h0p = blockIdx.y * 16;
    const int zb = blockIdx.z * DSPLIT;
    const int dend = min(zb + DSPLIT, DOUT);
    const int pix = (h0p + ty) * WOUT + (w0p + tx);
    const unsigned short* xus = (const unsigned short*)xin;

    __shared__ __align__(16) float su[SUWORDS];

    // ---- staging job decode (once): j = dl*80 + r*4 + seg (seg fastest) ----
    int jb_lds[4], jb_row[4], jb_dl[4];
    bool jb_load[4], jb_act[4];
    uint4 dat[4];
#pragma unroll
    for (int k = 0; k < 4; ++k) {
        int j = tid + k * 256;
        bool act = j < NJOBS;
        int jj = act ? j : 0;
        int seg = jj & 3;
        int rowjob = jj >> 2; // dl*20 + r
        int r = rowjob % ROWS;
        int dl = rowjob / ROWS;
        int gh = h0p - 2 + r;
        int gwb = w0p - 8 + seg * 8; // 8-aligned -> 16B-aligned byte addr
        jb_act[k] = act;
        jb_dl[k] = dl;
        jb_lds[k] = (r * ROWSTRIDE + seg * 8) * PIXSTRIDE + dl;
        jb_row[k] = gh * WOUT + gwb;
        jb_load[k] =
            act && gh >= 0 && gh < HOUT && gwb >= 0 && (gwb + 8) <= WOUT;
    }

    auto load_chunk = [&](int d0) {
#pragma unroll
        for (int k = 0; k < 4; ++k) {
            int gd = d0 - 1 + jb_dl[k];
            uint4 v = make_uint4(0u, 0u, 0u, 0u);
            if (jb_load[k] && gd >= 0 && gd < DOUT)
                v = *(const uint4*)(xus + (size_t)gd * NPIX + jb_row[k]);
            dat[k] = v;
        }
    };

    auto write_lds = [&]() {
#pragma unroll
        for (int k = 0; k < 4; ++k) {
            if (jb_act[k]) {
                int base = jb_lds[k];
                unsigned q;
                q = dat[k].x;
                su[base + 0 * PIXSTRIDE] = __uint_as_float(q << 16);
                su[base + 1 * PIXSTRIDE] = __uint_as_float(q & 0xFFFF0000u);
                q = dat[k].y;
                su[base + 2 * PIXSTRIDE] = __uint_as_float(q << 16);
                su[base + 3 * PIXSTRIDE] = __uint_as_float(q & 0xFFFF0000u);
                q = dat[k].z;
                su[base + 4 * PIXSTRIDE] = __uint_as_float(q << 16);
                su[base + 5 * PIXSTRIDE] = __uint_as_float(q & 0xFFFF0000u);
                q = dat[k].w;
                su[base + 6 * PIXSTRIDE] = __uint_as_float(q << 16);
                su[base + 7 * PIXSTRIDE] = __uint_as_float(q & 0xFFFF0000u);
            }
        }
    };

    // Prologue staging loads first (long-latency), then guidance prep.
    load_chunk(zb);

    // ---- guidance: two passes over lg1 to keep register pressure low ----
    float asum = 0.f;
#pragma unroll
    for (int ch = 0; ch < 75; ++ch) asum += fabsf(lg1[ch * NPIX + pix]);
    float inv = 1.f / fmaxf(asum, 1e-12f);
    unsigned gp[39]; // 3 sections x 13 bf16-pairs
#pragma unroll
    for (int s = 0; s < 3; ++s)
#pragma unroll
        for (int p = 0; p < 13; ++p) {
            int c0 = s * 25 + 2 * p;
            float w0 = lg1[c0 * NPIX + pix] * inv;
            float w1 = (2 * p + 1 < 25) ? lg1[(c0 + 1) * NPIX + pix] * inv : 0.f;
            gp[s * 13 + p] =
                (unsigned)bf16bits(w0) | ((unsigned)bf16bits(w1) << 16);
        }

    const int pbase = (ty * ROWSTRIDE + tx + 6) * PIXSTRIDE;

    for (int d0 = zb; d0 < dend; d0 += 8) {
        __syncthreads(); // previous chunk's readers done
        write_lds();
        __syncthreads();
        if (d0 + 8 < dend) load_chunk(d0 + 8); // prefetch (hidden by compute)

        float acc[8] = {0.f, 0.f, 0.f, 0.f, 0.f, 0.f, 0.f, 0.f};
#pragma unroll
        for (int i = 0; i < 5; ++i) {
#pragma unroll
            for (int j = 0; j < 5; ++j) {
                const int t = i * 5 + j;
                const float* sp =
                    su + pbase + (i * ROWSTRIDE + j) * PIXSTRIDE;
                float4 va = *(const float4*)sp;
                float4 vb = *(const float4*)(sp + 4);
                float2 vc = *(const float2*)(sp + 8);
                float v[10] = {va.x, va.y, va.z, va.w, vb.x,
                               vb.y, vb.z, vb.w, vc.x, vc.y};
                unsigned q0 = gp[t >> 1], q1 = gp[13 + (t >> 1)],
                         q2 = gp[26 + (t >> 1)];
                float g0 = __uint_as_float((t & 1) ? (q0 & 0xFFFF0000u)
                                                   : (q0 << 16));
                float g1 = __uint_as_float((t & 1) ? (q1 & 0xFFFF0000u)
                                                   : (q1 << 16));
                float g2 = __uint_as_float((t & 1) ? (q2 & 0xFFFF0000u)
                                                   : (q2 << 16));
#pragma unroll
                for (int dd = 0; dd < 8; ++dd)
                    acc[dd] += g1 * v[dd] + g0 * v[dd + 1] + g2 * v[dd + 2];
            }
        }

#pragma unroll
        for (int dd = 0; dd < 8; ++dd) {
            int d = d0 + dd;
            if (d < dend)
                yout[(size_t)d * NPIX + pix] = __float2bfloat16(acc[dd]);
        }
    }
}

// ---------------------------------------------------------------------------
// Kernel 4: softmin + disparity regression. Block = 64 px x 4 d-partials.
// ---------------------------------------------------------------------------
__global__ __launch_bounds__(256) void reduce_kernel(
    const __hip_bfloat16* __restrict__ y, float* __restrict__ out) {
    __shared__ float sm[4][64], sl[4][64], ss[4][64];
    const int lane = threadIdx.x & 63;
    const int part = threadIdx.x >> 6;
    const int px = blockIdx.x * 64 + lane;
    const int dstart = part * 49;
    const int dcnt = min(49, DOUT - dstart);
    const unsigned short* yu =
        (const unsigned short*)y + (size_t)dstart * NPIX + px;

    float m = -1e30f, l = 0.f, s = 0.f;
    for (int q = 0; q < dcnt; ++q) {
        float v = -__uint_as_float(((unsigned)yu[(size_t)q * NPIX]) << 16);
        float mx = fmaxf(m, v);
        float sc = __expf(m - mx);
        float e = __expf(v - mx);
        l = l * sc + e;
        s = s * sc + e * (float)(dstart + q);
        m = mx;
    }
    sm[part][lane] = m;
    sl[part][lane] = l;
    ss[part][lane] = s;
    __syncthreads();
    if (part == 0) {
        float M = m;
#pragma unroll
        for (int q = 1; q < 4; ++q) M = fmaxf(M, sm[q][lane]);
        float L = 0.f, S = 0.f;
#pragma unroll
        for (int q = 0; q < 4; ++q) {
            float w = __expf(sm[q][lane] - M);
            L += sl[q][lane] * w;
            S += ss[q][lane] * w;
        }
        out[px] = S / L;
    }
}

// ---------------------------------------------------------------------------
extern "C" void kernel_launch(void* const* d_in, const int* in_sizes, int n_in,
                              void* d_out, int out_size, void* d_ws,
                              size_t ws_size, hipStream_t stream) {
    const float* x = (const float*)d_in[0];
    const float* lg1 = (const float*)d_in[1];
    const float* cw = (const float*)d_in[2];
    float* out = (float*)d_out;

    // ws: c fp32 [100352] | u bf16 [NUPS] | y1 bf16 [NUPS]; LGA2 -> u buffer.
    float* c = (float*)d_ws;
    __hip_bfloat16* u = (__hip_bfloat16*)((char*)d_ws + (size_t)NCONV * 4);
    __hip_bfloat16* y1 = u + (size_t)NUPS;

    conv3d_kernel<<<(NCONV + 255) / 256, 256, 0, stream>>>(x, cw, c);
    upsample_kernel<<<(DOUT * HOUT * 64 + 255) / 256, 256, 0, stream>>>(c, u);

    dim3 grid(WOUT / 16, HOUT / 16, NZ); // 32 x 16 x 5 = 2560 blocks
    lga_kernel<<<grid, 256, 0, stream>>>(u, lg1, y1);
    lga_kernel<<<grid, 256, 0, stream>>>(y1, lg1, u);

    reduce_kernel<<<NPIX / 64, 256, 0, stream>>>(u, out);
}

// Round 5
// 663.992 us; speedup vs baseline: 6.2087x; 6.2087x over previous
//
#include <hip/hip_runtime.h>
#include <hip/hip_bf16.h>

#define DIN 49
#define HIN 32
#define WIN 64
#define CIN 32
#define DOUT 193
#define HOUT 256
#define WOUT 512
#define NPIX (HOUT * WOUT)      // 131072
#define NUPS (DOUT * NPIX)      // 25296896
#define NCONV (DIN * HIN * WIN) // 100352
#define DSPLIT 64
#define NZ 4 // 3 full z-slices of 64 + 1-plane tail (d=192)

// LGA LDS geometry: d-contiguous per pixel.
#define ROWS 20      // h halo rows
#define ROWSTRIDE 33 // pixel-row stride in pixels
#define PIXSTRIDE 12 // words per pixel (10 planes + 2 pad; 48 B, 16B-aligned)
#define NJOBS 800    // 10 planes * 20 rows * 4 segs
#define SUWORDS 7920

// ---------------------------------------------------------------------------
// Kernel 1: 3x3x3 conv, 32 -> 1 channels, zero pad 1, fp32 accumulate.
// ---------------------------------------------------------------------------
__global__ void conv3d_kernel(const float* __restrict__ x,
                              const float* __restrict__ w,
                              float* __restrict__ c) {
    __shared__ float ws[CIN * 27];
    for (int t = threadIdx.x; t < CIN * 27; t += blockDim.x)
        ws[t] = w[t];
    __syncthreads();

    int idx = blockIdx.x * blockDim.x + threadIdx.x;
    if (idx >= NCONV) return;
    int wq = idx % WIN;
    int t2 = idx / WIN;
    int hq = t2 % HIN;
    int dq = t2 / HIN;

    float acc = 0.f;
    for (int ci = 0; ci < CIN; ++ci) {
        const float* xb = x + ci * NCONV;
        const float* wb = ws + ci * 27;
#pragma unroll
        for (int kd = 0; kd < 3; ++kd) {
            int zd = dq + kd - 1;
            if (zd < 0 || zd >= DIN) continue;
#pragma unroll
            for (int kh = 0; kh < 3; ++kh) {
                int zh = hq + kh - 1;
                if (zh < 0 || zh >= HIN) continue;
#pragma unroll
                for (int kw = 0; kw < 3; ++kw) {
                    int zw = wq + kw - 1;
                    if (zw < 0 || zw >= WIN) continue;
                    acc += xb[(zd * HIN + zh) * WIN + zw] *
                           wb[(kd * 3 + kh) * 3 + kw];
                }
            }
        }
    }
    c[idx] = acc;
}

// ---------------------------------------------------------------------------
// Kernel 2: trilinear upsample, 8 outputs/thread along w, uint4 stores.
// ---------------------------------------------------------------------------
__global__ void upsample_kernel(const float* __restrict__ c,
                                __hip_bfloat16* __restrict__ u) {
    int t = blockIdx.x * blockDim.x + threadIdx.x;
    int wc = t & 63;
    int rest = t >> 6;
    int hh = rest & 255;
    int dd = rest >> 8;
    if (dd >= DOUT) return;

    float fd = (dd + 0.5f) * (49.0f / 193.0f) - 0.5f;
    fd = fminf(fmaxf(fd, 0.f), (float)(DIN - 1));
    int d0 = min((int)fd, DIN - 2);
    float ad = fd - (float)d0;

    float fh = (hh + 0.5f) * 0.125f - 0.5f;
    fh = fminf(fmaxf(fh, 0.f), (float)(HIN - 1));
    int h0 = min((int)fh, HIN - 2);
    float ah = fh - (float)h0;

    int cm1 = max(wc - 1, 0);
    int cp1 = min(wc + 1, WIN - 1);
    const float* p00 = c + (d0 * HIN + h0) * WIN;
    const float* p01 = p00 + WIN;
    const float* p10 = p00 + HIN * WIN;
    const float* p11 = p10 + WIN;

    float a[3];
    {
        float q00, q01, q10, q11;
        q00 = p00[cm1]; q01 = p01[cm1]; q10 = p10[cm1]; q11 = p11[cm1];
        a[0] = (q00 + ah * (q01 - q00)) * (1.f - ad) +
               (q10 + ah * (q11 - q10)) * ad;
        q00 = p00[wc]; q01 = p01[wc]; q10 = p10[wc]; q11 = p11[wc];
        a[1] = (q00 + ah * (q01 - q00)) * (1.f - ad) +
               (q10 + ah * (q11 - q10)) * ad;
        q00 = p00[cp1]; q01 = p01[cp1]; q10 = p10[cp1]; q11 = p11[cp1];
        a[2] = (q00 + ah * (q01 - q00)) * (1.f - ad) +
               (q10 + ah * (q11 - q10)) * ad;
    }

    union {
        unsigned short us[8];
        uint4 v4;
    } pk;
#pragma unroll
    for (int i = 0; i < 8; ++i) {
        float fw = (float)(wc * 8 + i) * 0.125f + (0.0625f - 0.5f);
        fw = fminf(fmaxf(fw, 0.f), (float)(WIN - 1));
        int w0 = min((int)fw, WIN - 2);
        float aw = fw - (float)w0;
        int idx = w0 - (wc - 1);
        float lo = (idx == 0) ? a[0] : a[1];
        float hi = (idx == 0) ? a[1] : a[2];
        float v = lo + aw * (hi - lo);
        __hip_bfloat16 b = __float2bfloat16(v);
        unsigned short usv;
        __builtin_memcpy(&usv, &b, 2);
        pk.us[i] = usv;
    }
    *((uint4*)(u + (size_t)dd * NPIX + hh * WOUT + wc * 8)) = pk.v4;
}

// ---------------------------------------------------------------------------
// LGA: 16x16 pixel tile x DSPLIT d-planes per block. d-contiguous LDS, wide
// ds_reads, coalesced 16B register-prefetched staging, bf16-packed guidance.
// NO forced occupancy: spilling is far worse than 1 fewer wave (round-4
// post-mortem: launch_bounds(256,3) -> 84 VGPR + scratch -> 5.3 GB HBM).
// ---------------------------------------------------------------------------
__device__ __forceinline__ unsigned short bf16bits(float f) {
    __hip_bfloat16 h = __float2bfloat16(f);
    unsigned short b;
    __builtin_memcpy(&b, &h, 2);
    return b;
}

__global__ __launch_bounds__(256) void lga_kernel(
    const __hip_bfloat16* __restrict__ xin,
    const float* __restrict__ lg1,
    __hip_bfloat16* __restrict__ yout) {
    const int tid = threadIdx.x;
    const int tx = tid & 15;
    const int ty = tid >> 4;
    const int w0p = blockIdx.x * 16;
    const int h0p = blockIdx.y * 16;
    const int zb = blockIdx.z * DSPLIT;
    const int dend = min(zb + DSPLIT, DOUT);
    const int pix = (h0p + ty) * WOUT + (w0p + tx);
    const unsigned short* xus = (const unsigned short*)xin;

    __shared__ __align__(16) float su[SUWORDS];

    // ---- staging job decode (once): j = dl*80 + r*4 + seg (seg fastest) ----
    // k = 0..2 always active; k = 3 active iff tid < 32 (NJOBS = 800).
    int jb_lds[4], jb_row[4], jb_dl[4];
    bool jb_inb[4]; // spatial in-bounds (gh, gw)
    uint4 dat[4];
#pragma unroll
    for (int k = 0; k < 4; ++k) {
        int j = tid + k * 256;
        int jj = (k == 3 && tid >= 32) ? 0 : j;
        int seg = jj & 3;
        int rowjob = jj >> 2; // dl*20 + r
        int r = rowjob % ROWS;
        int dl = rowjob / ROWS;
        int gh = h0p - 2 + r;
        int gwb = w0p - 8 + seg * 8; // 8-aligned -> 16B-aligned byte addr
        jb_dl[k] = dl;
        jb_lds[k] = (r * ROWSTRIDE + seg * 8) * PIXSTRIDE + dl;
        jb_row[k] = gh * WOUT + gwb;
        jb_inb[k] = gh >= 0 && gh < HOUT && gwb >= 0 && (gwb + 8) <= WOUT;
    }
    const bool k3act = (tid < 32);

    auto load_chunk = [&](int d0) {
#pragma unroll
        for (int k = 0; k < 4; ++k) {
            int gd = d0 - 1 + jb_dl[k];
            uint4 v = make_uint4(0u, 0u, 0u, 0u);
            if (jb_inb[k] && gd >= 0 && gd < DOUT && (k < 3 || k3act))
                v = *(const uint4*)(xus + (size_t)gd * NPIX + jb_row[k]);
            dat[k] = v;
        }
    };

    auto write_lds = [&]() {
#pragma unroll
        for (int k = 0; k < 4; ++k) {
            if (k < 3 || k3act) {
                int base = jb_lds[k];
                unsigned q;
                q = dat[k].x;
                su[base + 0 * PIXSTRIDE] = __uint_as_float(q << 16);
                su[base + 1 * PIXSTRIDE] = __uint_as_float(q & 0xFFFF0000u);
                q = dat[k].y;
                su[base + 2 * PIXSTRIDE] = __uint_as_float(q << 16);
                su[base + 3 * PIXSTRIDE] = __uint_as_float(q & 0xFFFF0000u);
                q = dat[k].z;
                su[base + 4 * PIXSTRIDE] = __uint_as_float(q << 16);
                su[base + 5 * PIXSTRIDE] = __uint_as_float(q & 0xFFFF0000u);
                q = dat[k].w;
                su[base + 6 * PIXSTRIDE] = __uint_as_float(q << 16);
                su[base + 7 * PIXSTRIDE] = __uint_as_float(q & 0xFFFF0000u);
            }
        }
    };

    // Prologue staging loads first (long-latency), then guidance prep.
    load_chunk(zb);

    // ---- guidance: two passes over lg1 to keep register pressure low ----
    float asum = 0.f;
#pragma unroll
    for (int ch = 0; ch < 75; ++ch) asum += fabsf(lg1[ch * NPIX + pix]);
    float inv = 1.f / fmaxf(asum, 1e-12f);
    unsigned gp[39]; // 3 sections x 13 bf16-pairs
#pragma unroll
    for (int s = 0; s < 3; ++s)
#pragma unroll
        for (int p = 0; p < 13; ++p) {
            int c0 = s * 25 + 2 * p;
            float w0 = lg1[c0 * NPIX + pix] * inv;
            float w1 = (2 * p + 1 < 25) ? lg1[(c0 + 1) * NPIX + pix] * inv : 0.f;
            gp[s * 13 + p] =
                (unsigned)bf16bits(w0) | ((unsigned)bf16bits(w1) << 16);
        }

    const int pbase = (ty * ROWSTRIDE + tx + 6) * PIXSTRIDE;

    for (int d0 = zb; d0 < dend; d0 += 8) {
        __syncthreads(); // previous chunk's readers done
        write_lds();
        __syncthreads();
        if (d0 + 8 < dend) load_chunk(d0 + 8); // prefetch (hidden by compute)

        float acc[8] = {0.f, 0.f, 0.f, 0.f, 0.f, 0.f, 0.f, 0.f};
#pragma unroll
        for (int i = 0; i < 5; ++i) {
#pragma unroll
            for (int j = 0; j < 5; ++j) {
                const int t = i * 5 + j;
                const float* sp =
                    su + pbase + (i * ROWSTRIDE + j) * PIXSTRIDE;
                float4 va = *(const float4*)sp;
                float4 vb = *(const float4*)(sp + 4);
                float2 vc = *(const float2*)(sp + 8);
                float v[10] = {va.x, va.y, va.z, va.w, vb.x,
                               vb.y, vb.z, vb.w, vc.x, vc.y};
                unsigned q0 = gp[t >> 1], q1 = gp[13 + (t >> 1)],
                         q2 = gp[26 + (t >> 1)];
                float g0 = __uint_as_float((t & 1) ? (q0 & 0xFFFF0000u)
                                                   : (q0 << 16));
                float g1 = __uint_as_float((t & 1) ? (q1 & 0xFFFF0000u)
                                                   : (q1 << 16));
                float g2 = __uint_as_float((t & 1) ? (q2 & 0xFFFF0000u)
                                                   : (q2 << 16));
#pragma unroll
                for (int dd = 0; dd < 8; ++dd)
                    acc[dd] += g1 * v[dd] + g0 * v[dd + 1] + g2 * v[dd + 2];
            }
        }

#pragma unroll
        for (int dd = 0; dd < 8; ++dd) {
            int d = d0 + dd;
            if (d < dend)
                yout[(size_t)d * NPIX + pix] = __float2bfloat16(acc[dd]);
        }
    }
}

// ---------------------------------------------------------------------------
// Kernel 4: softmin + disparity regression. Block = 64 px x 4 d-partials.
// ---------------------------------------------------------------------------
__global__ __launch_bounds__(256) void reduce_kernel(
    const __hip_bfloat16* __restrict__ y, float* __restrict__ out) {
    __shared__ float sm[4][64], sl[4][64], ss[4][64];
    const int lane = threadIdx.x & 63;
    const int part = threadIdx.x >> 6;
    const int px = blockIdx.x * 64 + lane;
    const int dstart = part * 49;
    const int dcnt = min(49, DOUT - dstart);
    const unsigned short* yu =
        (const unsigned short*)y + (size_t)dstart * NPIX + px;

    float m = -1e30f, l = 0.f, s = 0.f;
    for (int q = 0; q < dcnt; ++q) {
        float v = -__uint_as_float(((unsigned)yu[(size_t)q * NPIX]) << 16);
        float mx = fmaxf(m, v);
        float sc = __expf(m - mx);
        float e = __expf(v - mx);
        l = l * sc + e;
        s = s * sc + e * (float)(dstart + q);
        m = mx;
    }
    sm[part][lane] = m;
    sl[part][lane] = l;
    ss[part][lane] = s;
    __syncthreads();
    if (part == 0) {
        float M = m;
#pragma unroll
        for (int q = 1; q < 4; ++q) M = fmaxf(M, sm[q][lane]);
        float L = 0.f, S = 0.f;
#pragma unroll
        for (int q = 0; q < 4; ++q) {
            float w = __expf(sm[q][lane] - M);
            L += sl[q][lane] * w;
            S += ss[q][lane] * w;
        }
        out[px] = S / L;
    }
}

// ---------------------------------------------------------------------------
extern "C" void kernel_launch(void* const* d_in, const int* in_sizes, int n_in,
                              void* d_out, int out_size, void* d_ws,
                              size_t ws_size, hipStream_t stream) {
    const float* x = (const float*)d_in[0];
    const float* lg1 = (const float*)d_in[1];
    const float* cw = (const float*)d_in[2];
    float* out = (float*)d_out;

    // ws: c fp32 [100352] | u bf16 [NUPS] | y1 bf16 [NUPS]; LGA2 -> u buffer.
    float* c = (float*)d_ws;
    __hip_bfloat16* u = (__hip_bfloat16*)((char*)d_ws + (size_t)NCONV * 4);
    __hip_bfloat16* y1 = u + (size_t)NUPS;

    conv3d_kernel<<<(NCONV + 255) / 256, 256, 0, stream>>>(x, cw, c);
    upsample_kernel<<<(DOUT * HOUT * 64 + 255) / 256, 256, 0, stream>>>(c, u);

    dim3 grid(WOUT / 16, HOUT / 16, NZ); // 32 x 16 x 4 = 2048 blocks
    lga_kernel<<<grid, 256, 0, stream>>>(u, lg1, y1);
    lga_kernel<<<grid, 256, 0, stream>>>(y1, lg1, u);

    reduce_kernel<<<NPIX / 64, 256, 0, stream>>>(u, out);
}